// Round 1
// baseline (337.538 us; speedup 1.0000x reference)
//
#include <hip/hip_runtime.h>
#include <math.h>

// PPCALayer fused kernel, MI355X (gfx950).
// x: [B=64, C=256, H*W=3136] fp32, weight: [3136, 15] fp32, out same shape as x.
// Per pixel (b,s): 15 multi-scale channel-group means -> normalize across the
// 15 features (ddof=0) -> dot with weight[s,:] -> sigmoid -> scale x[b,:,s].
//
// Strategy: one block per (b, 64-spatial tile). Stage the 256x64 fp32 tile
// (64 KB) in LDS with float4 loads, reduce channel-group sums from LDS,
// compute gate, multiply+store with float4. Exactly read-once + write-once
// HBM traffic (411 MB total) -> memory-bound roofline ~65 us.

constexpr int C_   = 256;
constexpr int HW_  = 3136;   // 56*56
constexpr int T_   = 64;     // spatial positions per block (49*64 = 3136 exact)
constexpr int TPB_ = HW_ / T_;  // 49 tiles per batch image
constexpr int B_   = 64;

__global__ __launch_bounds__(256, 2) void ppca_fused(
    const float* __restrict__ x, const float* __restrict__ wgt,
    float* __restrict__ out)
{
  __shared__ __align__(16) float tile[C_ * T_];  // 64 KB: [channel][spatial]
  __shared__ float S[8 * T_];                    // eight 32-channel sums per spatial
  __shared__ float gate[T_];

  const int blk = blockIdx.x;
  const int b   = blk / TPB_;
  const int til = blk - b * TPB_;
  const int sp0 = til * T_;
  const size_t base = (size_t)b * C_ * HW_ + sp0;
  const float* xb = x + base;
  float* ob = out + base;

  const int t   = threadIdx.x;
  const int sp4 = t & 15;   // which float4 (4 spatial) within the tile
  const int c0  = t >> 4;   // 0..15; channel = c0 + 16*i

  // ---- Phase 1: stage tile to LDS. Coalesced: lanes 0..15 cover one
  // contiguous 256B channel row; a wave covers 4 rows. All 16 loads issued
  // before any LDS write so they overlap in flight.
  float4 v[16];
  #pragma unroll
  for (int i = 0; i < 16; ++i) {
    const int c = c0 + (i << 4);
    v[i] = *(const float4*)(xb + (size_t)c * HW_ + (sp4 << 2));
  }
  #pragma unroll
  for (int i = 0; i < 16; ++i) {
    const int c = c0 + (i << 4);
    *(float4*)(&tile[c * T_ + (sp4 << 2)]) = v[i];
  }
  __syncthreads();

  // ---- Phase 1b: wave w -> channels [64w, 64w+64); lane l -> spatial l.
  // LDS addr (ch*64 + l): lanes l and l+32 alias the same bank (2-way = free).
  {
    const int w = t >> 6;
    const int l = t & 63;
    float s0 = 0.f, s1 = 0.f;
    #pragma unroll
    for (int k = 0; k < 32; ++k) s0 += tile[(w * 64 + k) * T_ + l];
    #pragma unroll
    for (int k = 0; k < 32; ++k) s1 += tile[(w * 64 + 32 + k) * T_ + l];
    S[(2 * w) * T_ + l]     = s0;
    S[(2 * w + 1) * T_ + l] = s1;
  }
  __syncthreads();

  // ---- Phase 1c: one wave computes the 64 gates.
  if (t < T_) {
    float Sg[8];
    #pragma unroll
    for (int g = 0; g < 8; ++g) Sg[g] = S[g * T_ + t];
    float p64[4];
    #pragma unroll
    for (int j = 0; j < 4; ++j) p64[j] = Sg[2 * j] + Sg[2 * j + 1];
    const float p128a = p64[0] + p64[1];
    const float p128b = p64[2] + p64[3];
    const float tot   = p128a + p128b;

    // feats order per SCALES=(1,2,4,8): [tot/256, 128-means x2, 64-means x4, 32-means x8]
    float f[15];
    f[0] = tot * (1.f / 256.f);
    f[1] = p128a * (1.f / 128.f);
    f[2] = p128b * (1.f / 128.f);
    #pragma unroll
    for (int j = 0; j < 4; ++j) f[3 + j] = p64[j] * (1.f / 64.f);
    #pragma unroll
    for (int g = 0; g < 8; ++g) f[7 + g] = Sg[g] * (1.f / 32.f);

    float m = 0.f;
    #pragma unroll
    for (int i = 0; i < 15; ++i) m += f[i];
    m *= (1.f / 15.f);
    float var = 0.f;
    #pragma unroll
    for (int i = 0; i < 15; ++i) { const float d = f[i] - m; var += d * d; }
    var *= (1.f / 15.f);
    const float inv = 1.f / sqrtf(var);

    const float* wp = wgt + (size_t)(sp0 + t) * 15;
    float z = 0.f;
    #pragma unroll
    for (int i = 0; i < 15; ++i) z += (f[i] - m) * wp[i];
    z *= inv;
    gate[t] = 1.f / (1.f + __expf(-z));
  }
  __syncthreads();

  // ---- Phase 2: multiply by gate, store (coalesced float4).
  const float4 g4 = *(const float4*)(&gate[sp4 << 2]);
  #pragma unroll
  for (int i = 0; i < 16; ++i) {
    const int c = c0 + (i << 4);
    float4 vv = *(const float4*)(&tile[c * T_ + (sp4 << 2)]);
    vv.x *= g4.x; vv.y *= g4.y; vv.z *= g4.z; vv.w *= g4.w;
    *(float4*)(ob + (size_t)c * HW_ + (sp4 << 2)) = vv;
  }
}

extern "C" void kernel_launch(void* const* d_in, const int* in_sizes, int n_in,
                              void* d_out, int out_size, void* d_ws, size_t ws_size,
                              hipStream_t stream) {
  const float* x = (const float*)d_in[0];      // [64,256,3136] fp32
  const float* w = (const float*)d_in[1];      // [3136,15] fp32
  float* out = (float*)d_out;                  // [64,256,3136] fp32
  (void)in_sizes; (void)n_in; (void)out_size; (void)d_ws; (void)ws_size;

  dim3 grid(B_ * TPB_);   // 3136 blocks
  dim3 block(256);
  ppca_fused<<<grid, block, 0, stream>>>(x, w, out);
}